// Round 9
// baseline (42.156 us; speedup 1.0000x reference)
//
#include <hip/hip_runtime.h>
#include <math.h>

// Input:  x (16, 31, 256, 256) float32
// Output: sqrt(v^2 + h^2 + 1e-6), v = x[y+1]-x[y-1], h = x[:,x+1]-x[:,x-1],
// zero padding at the borders.
//
// R9: de-phasing experiment. Same per-wave work as R6 (STRIP=8, cached loads,
// NT stores, XCD swizzle, sched_barrier load batch, v_sqrt) but 128-thread
// blocks and 7936 blocks -> 4 staggered block-generations per CU, so loads of
// some blocks continuously overlap NT-stores of others (R6/R8 had machine-
// wide synchronized load->compute->store phases = alternating read/write
// bursts at DRAM, paying bus turnaround).

#define IMG_H 256
#define IMG_W 256
#define EPS   1e-6f
#define STRIP 8                    // output rows per wave/lane
#define WAVES_PER_BLOCK 2
#define ROWS_PER_BLOCK (STRIP * WAVES_PER_BLOCK)   // 16
#define BANDS (IMG_H / ROWS_PER_BLOCK)             // 16

typedef float f32x4 __attribute__((ext_vector_type(4)));

__global__ __launch_bounds__(128) void grad_mag_kernel(
    const float* __restrict__ in, float* __restrict__ out)
{
    const int tid  = threadIdx.x;
    const int lane = tid & 63;
    const int wv   = tid >> 6;                    // wave within block: 0..1

    // XCD-chunked swizzle (bijective: gridDim.x = 7936 divisible by 8).
    const int chunk = gridDim.x >> 3;
    const int sid   = (blockIdx.x & 7) * chunk + (blockIdx.x >> 3);

    const int band        = sid & (BANDS - 1);
    const long long plane = sid >> 4;             // 0..495  (16 bands/plane)

    const int y0 = band * ROWS_PER_BLOCK + wv * STRIP;  // first output row
    const int x0 = lane * 4;

    const float* __restrict__ p = in  + plane * (long long)(IMG_H * IMG_W) + x0;
    float*       __restrict__ q = out + plane * (long long)(IMG_H * IMG_W) + x0;

    // Load rows y0-1 .. y0+STRIP unconditionally from clamped addresses
    // (branch-free, back-to-back issue -> 10 outstanding loads per lane).
    f32x4 r[STRIP + 2];
    #pragma unroll
    for (int i = 0; i < STRIP + 2; ++i) {
        const int y  = y0 - 1 + i;
        const int yc = y < 0 ? 0 : (y > IMG_H - 1 ? IMG_H - 1 : y);
        r[i] = *reinterpret_cast<const f32x4*>(p + (long long)yc * IMG_W);
    }
    // Keep the load batch together — do not let compute interleave upward.
    __builtin_amdgcn_sched_barrier(0);

    #pragma unroll
    for (int i = 0; i < STRIP + 2; ++i) {
        const int y = y0 - 1 + i;
        if (y < 0 || y > IMG_H - 1) r[i] = (f32x4)0.f;
    }

    #pragma unroll
    for (int i = 0; i < STRIP; ++i) {
        const f32x4 up  = r[i];
        const f32x4 cur = r[i + 1];
        const f32x4 dn  = r[i + 2];

        // Horizontal neighbors across lanes (wave spans exactly one row).
        float left  = __shfl_up(cur.w, 1);
        float right = __shfl_down(cur.x, 1);
        if (lane == 0)  left  = 0.f;     // zero pad at x = -1
        if (lane == 63) right = 0.f;     // zero pad at x = 256

        f32x4 h, v, o;
        h.x = cur.y - left;
        h.y = cur.z - cur.x;
        h.z = cur.w - cur.y;
        h.w = right - cur.z;
        v = dn - up;

        o.x = __builtin_amdgcn_sqrtf(v.x * v.x + h.x * h.x + EPS);
        o.y = __builtin_amdgcn_sqrtf(v.y * v.y + h.y * h.y + EPS);
        o.z = __builtin_amdgcn_sqrtf(v.z * v.z + h.z * h.z + EPS);
        o.w = __builtin_amdgcn_sqrtf(v.w * v.w + h.w * h.w + EPS);

        __builtin_nontemporal_store(
            o, reinterpret_cast<f32x4*>(q + (long long)(y0 + i) * IMG_W));
    }
}

extern "C" void kernel_launch(void* const* d_in, const int* in_sizes, int n_in,
                              void* d_out, int out_size, void* d_ws, size_t ws_size,
                              hipStream_t stream)
{
    const float* x = (const float*)d_in[0];
    float* out = (float*)d_out;

    const int planes = in_sizes[0] / (IMG_H * IMG_W);        // 16*31 = 496
    const int grid   = planes * BANDS;                       // 496 * 16 = 7936

    grad_mag_kernel<<<grid, 128, 0, stream>>>(x, out);
}

// Round 10
// 40.791 us; speedup vs baseline: 1.0335x; 1.0335x over previous
//
#include <hip/hip_runtime.h>
#include <math.h>

// Input:  x (16, 31, 256, 256) float32
// Output: sqrt(v^2 + h^2 + 1e-6), v = x[y+1]-x[y-1], h = x[:,x+1]-x[:,x-1],
// zero padding at the borders.
//
// R10 = R6 revert (best measured config, 40.85 us). Session ledger:
//   R1 baseline shuffle kernel ............ 71.3 us
//   R2 8-row register strip ............... 45.0
//   R3 +XCD swizzle, STRIP=16, v_sqrt ..... 43.2
//   R4 regular stores (L3 thrash) ......... 48.4  [reverted]
//   R5 +sched_barrier MLP pin ............. 42.3
//   R6 STRIP=8 x 256-thd, 2 generations ... 40.9  <-- best
//   R7 NT loads + reg stores .............. 47.6  [reverted]
//   R8 persistent blocks x2 ............... 42.1  [reverted]
//   R9 de-phased 128-thd blocks ........... 42.2  [reverted]
// Steady state: FETCH 63.5 MB (L3 absorbs ~half the input re-reads),
// WRITE 127 MB (compulsory, NT), 4.66 TB/s effective on a 1:2 rd:wr mix.
// Cache-policy, MLP, strip-depth, and wave-structure axes all explored;
// every alternative within +-3% or worse. This is the HIP-level floor.

#define IMG_H 256
#define IMG_W 256
#define EPS   1e-6f
#define STRIP 8                    // output rows per wave/lane
#define WAVES_PER_BLOCK 4
#define ROWS_PER_BLOCK (STRIP * WAVES_PER_BLOCK)   // 32
#define BANDS (IMG_H / ROWS_PER_BLOCK)             // 8

typedef float f32x4 __attribute__((ext_vector_type(4)));

__global__ __launch_bounds__(256) void grad_mag_kernel(
    const float* __restrict__ in, float* __restrict__ out)
{
    const int tid  = threadIdx.x;
    const int lane = tid & 63;
    const int wv   = tid >> 6;                    // wave within block: 0..3

    // XCD-chunked swizzle (bijective: gridDim.x = 3968 divisible by 8).
    const int chunk = gridDim.x >> 3;
    const int sid   = (blockIdx.x & 7) * chunk + (blockIdx.x >> 3);

    const int band        = sid & (BANDS - 1);
    const long long plane = sid >> 3;             // 0..495

    const int y0 = band * ROWS_PER_BLOCK + wv * STRIP;  // first output row
    const int x0 = lane * 4;

    const float* __restrict__ p = in  + plane * (long long)(IMG_H * IMG_W) + x0;
    float*       __restrict__ q = out + plane * (long long)(IMG_H * IMG_W) + x0;

    // Load rows y0-1 .. y0+STRIP unconditionally from clamped addresses
    // (branch-free, back-to-back issue -> 10 outstanding loads per lane).
    f32x4 r[STRIP + 2];
    #pragma unroll
    for (int i = 0; i < STRIP + 2; ++i) {
        const int y  = y0 - 1 + i;
        const int yc = y < 0 ? 0 : (y > IMG_H - 1 ? IMG_H - 1 : y);
        r[i] = *reinterpret_cast<const f32x4*>(p + (long long)yc * IMG_W);
    }
    // Keep the load batch together — do not let compute interleave upward.
    __builtin_amdgcn_sched_barrier(0);

    #pragma unroll
    for (int i = 0; i < STRIP + 2; ++i) {
        const int y = y0 - 1 + i;
        if (y < 0 || y > IMG_H - 1) r[i] = (f32x4)0.f;
    }

    #pragma unroll
    for (int i = 0; i < STRIP; ++i) {
        const f32x4 up  = r[i];
        const f32x4 cur = r[i + 1];
        const f32x4 dn  = r[i + 2];

        // Horizontal neighbors across lanes (wave spans exactly one row).
        float left  = __shfl_up(cur.w, 1);
        float right = __shfl_down(cur.x, 1);
        if (lane == 0)  left  = 0.f;     // zero pad at x = -1
        if (lane == 63) right = 0.f;     // zero pad at x = 256

        f32x4 h, v, o;
        h.x = cur.y - left;
        h.y = cur.z - cur.x;
        h.z = cur.w - cur.y;
        h.w = right - cur.z;
        v = dn - up;

        o.x = __builtin_amdgcn_sqrtf(v.x * v.x + h.x * h.x + EPS);
        o.y = __builtin_amdgcn_sqrtf(v.y * v.y + h.y * h.y + EPS);
        o.z = __builtin_amdgcn_sqrtf(v.z * v.z + h.z * h.z + EPS);
        o.w = __builtin_amdgcn_sqrtf(v.w * v.w + h.w * h.w + EPS);

        __builtin_nontemporal_store(
            o, reinterpret_cast<f32x4*>(q + (long long)(y0 + i) * IMG_W));
    }
}

extern "C" void kernel_launch(void* const* d_in, const int* in_sizes, int n_in,
                              void* d_out, int out_size, void* d_ws, size_t ws_size,
                              hipStream_t stream)
{
    const float* x = (const float*)d_in[0];
    float* out = (float*)d_out;

    const int planes = in_sizes[0] / (IMG_H * IMG_W);        // 16*31 = 496
    const int grid   = planes * BANDS;                       // 496 * 8 = 3968

    grad_mag_kernel<<<grid, 256, 0, stream>>>(x, out);
}